// Round 3
// baseline (1762.336 us; speedup 1.0000x reference)
//
#include <hip/hip_runtime.h>
#include <math.h>

#define NP   100000
#define EDG  1600000
#define NK   15
#define SIGK 0.04f
#define SCH  2048
#define SNB  49            // ceil(NP/SCH)
#define AK   68            // padded agg row (floats)
#define MAXE 384           // max edges per 16-query block (mean 256, sigma 16)

typedef __bf16 v8bf __attribute__((ext_vector_type(8)));
typedef __bf16 bf4  __attribute__((ext_vector_type(4)));
typedef float  v4f  __attribute__((ext_vector_type(4)));
typedef _Float16 half_t;

__device__ __forceinline__ float lk(float v) { return v >= 0.f ? v : 0.1f * v; }
__device__ __forceinline__ float bf2f(__bf16 b) { return (float)b; }

// ---------------------------------------------------------------------------
// MFMA GEMM: Out[n x Ntot] = X[n x KIN] @ W, W preshuffled bf16 B-frags.
// Block 256 thr = 4 waves; tile 128 rows x NB cols; wave = 32 rows x NB cols.
// TRANS: X' = leaky(ta*X+tb) on stage. OUTBF: write bf16. Col stats fused:
// per-block reduce -> 1 atomicAdd per col into osum/osq.
// ---------------------------------------------------------------------------
template <int KIN, int NB, bool TRANS, bool OUTBF>
__global__ __launch_bounds__(256) void mgemm_k(const float* __restrict__ X,
                                               const __bf16* __restrict__ Wp,
                                               void* __restrict__ Out, int n, int Ntot,
                                               const float* __restrict__ ta,
                                               const float* __restrict__ tb,
                                               float* __restrict__ osum,
                                               float* __restrict__ osq) {
  constexpr int PITCH = KIN + 8;
  constexpr int NT = NB / 16;
  __shared__ __bf16 al[128 * PITCH];
  __shared__ float red[2][NB][4];
  const int tid = threadIdx.x;
  const int r0 = blockIdx.x << 7;
  const int nb0 = blockIdx.y * NB;

  // stage A tile: fp32 -> (affine/leaky) -> bf16
  constexpr int QKS = (KIN == 128) ? 5 : 4;  // log2(KIN/4)
  for (int idx = tid; idx < (128 << QKS); idx += 256) {
    const int r = idx >> QKS, q = (idx & ((1 << QKS) - 1)) << 2;
    const int row = r0 + r;
    float4 v = make_float4(0.f, 0.f, 0.f, 0.f);
    if (row < n) {
      v = *(const float4*)&X[(size_t)row * KIN + q];
      if (TRANS) {
        v.x = lk(ta[q + 0] * v.x + tb[q + 0]);
        v.y = lk(ta[q + 1] * v.y + tb[q + 1]);
        v.z = lk(ta[q + 2] * v.z + tb[q + 2]);
        v.w = lk(ta[q + 3] * v.w + tb[q + 3]);
      }
    }
    bf4 o;
    o[0] = (__bf16)v.x; o[1] = (__bf16)v.y; o[2] = (__bf16)v.z; o[3] = (__bf16)v.w;
    *(bf4*)&al[r * PITCH + q] = o;
  }
  __syncthreads();

  const int wv = tid >> 6, lane = tid & 63;
  const int mr = lane & 15, quad = lane >> 4;
  const int ntg0 = nb0 >> 4;
  const int NTG = Ntot >> 4;
  v4f acc[2][NT];
#pragma unroll
  for (int a = 0; a < 2; ++a)
#pragma unroll
    for (int b = 0; b < NT; ++b) acc[a][b] = (v4f){0.f, 0.f, 0.f, 0.f};

#pragma unroll
  for (int ks = 0; ks < KIN / 32; ++ks) {
    v8bf bf[NT];
#pragma unroll
    for (int nt = 0; nt < NT; ++nt)
      bf[nt] = ((const v8bf*)Wp)[((size_t)ks * NTG + ntg0 + nt) * 64 + lane];
#pragma unroll
    for (int mt = 0; mt < 2; ++mt) {
      const int row = (wv << 5) + (mt << 4) + mr;
      const v8bf av = *(const v8bf*)&al[row * PITCH + (ks << 5) + (quad << 3)];
#pragma unroll
      for (int nt = 0; nt < NT; ++nt)
        acc[mt][nt] = __builtin_amdgcn_mfma_f32_16x16x32_bf16(av, bf[nt], acc[mt][nt], 0, 0, 0);
    }
  }

  // epilogue: write + column stats (padded rows are exactly 0 -> stats safe)
  float csum[NT], csq[NT];
#pragma unroll
  for (int nt = 0; nt < NT; ++nt) { csum[nt] = 0.f; csq[nt] = 0.f; }
#pragma unroll
  for (int mt = 0; mt < 2; ++mt)
#pragma unroll
    for (int nt = 0; nt < NT; ++nt)
#pragma unroll
      for (int r = 0; r < 4; ++r) {
        const float v = acc[mt][nt][r];
        const int row = r0 + (wv << 5) + (mt << 4) + (quad << 2) + r;
        if (row < n) {
          const size_t o = (size_t)row * Ntot + nb0 + (nt << 4) + mr;
          if (OUTBF) ((__bf16*)Out)[o] = (__bf16)v;
          else       ((float*)Out)[o] = v;
        }
        csum[nt] += v;
        csq[nt] += v * v;
      }
#pragma unroll
  for (int nt = 0; nt < NT; ++nt) {
    float s = csum[nt], q = csq[nt];
    s += __shfl_down(s, 32); s += __shfl_down(s, 16);
    q += __shfl_down(q, 32); q += __shfl_down(q, 16);
    if (quad == 0) { red[0][(nt << 4) + mr][wv] = s; red[1][(nt << 4) + mr][wv] = q; }
  }
  __syncthreads();
  if (tid < NB) {
    const float s = red[0][tid][0] + red[0][tid][1] + red[0][tid][2] + red[0][tid][3];
    const float q = red[1][tid][0] + red[1][tid][1] + red[1][tid][2] + red[1][tid][3];
    atomicAdd(&osum[nb0 + tid], s);
    atomicAdd(&osq[nb0 + tid], q);
  }
}

// ---------------------------------------------------------------------------
// BN stats (only for kpagg output) + fold + normalize kernels
// ---------------------------------------------------------------------------
template <int C>
__global__ __launch_bounds__(256) void colstats_k(const float* __restrict__ T, int total,
                                                  float* __restrict__ sum,
                                                  float* __restrict__ sq) {
  __shared__ float s1[256], s2[256];
  const int tid = threadIdx.x;
  const int stride = gridDim.x << 8;
  float a = 0.f, b = 0.f;
  for (int idx = (blockIdx.x << 8) + tid; idx < total; idx += stride) {
    const float v = T[idx];
    a += v;
    b += v * v;
  }
  s1[tid] = a; s2[tid] = b;
  __syncthreads();
  for (int s = 128; s >= C; s >>= 1) {
    if (tid < s) { s1[tid] += s1[tid + s]; s2[tid] += s2[tid + s]; }
    __syncthreads();
  }
  if (tid < C) { atomicAdd(&sum[tid], s1[tid]); atomicAdd(&sq[tid], s2[tid]); }
}

__global__ void finalize_k(const float* __restrict__ sum, const float* __restrict__ sq,
                           const float* __restrict__ g, const float* __restrict__ b,
                           float* __restrict__ oa, float* __restrict__ ob, int C,
                           float invn) {
  const int c = threadIdx.x;
  if (c < C) {
    const float m = sum[c] * invn;
    const float var = sq[c] * invn - m * m;
    const float a = g[c] / sqrtf(var + 1e-5f);
    oa[c] = a;
    ob[c] = b[c] - m * a;
  }
}

// hbuf fp32 -> hb bf16 with affine+leaky
__global__ __launch_bounds__(256) void normleaky_k(const float* __restrict__ t,
                                                   __bf16* __restrict__ hb,
                                                   const float* __restrict__ a,
                                                   const float* __restrict__ b) {
  const int idx = (blockIdx.x << 8) + threadIdx.x;
  const int c = (idx << 2) & 63;
  float4 v = ((const float4*)t)[idx];
  bf4 o;
  o[0] = (__bf16)lk(a[c + 0] * v.x + b[c + 0]);
  o[1] = (__bf16)lk(a[c + 1] * v.y + b[c + 1]);
  o[2] = (__bf16)lk(a[c + 2] * v.z + b[c + 2]);
  o[3] = (__bf16)lk(a[c + 3] * v.w + b[c + 3]);
  *(bf4*)&hb[(size_t)idx << 2] = o;
}

// out = leaky(a2*t2+b2) + asc*tsc+bsc   (t2, tsc bf16)
__global__ __launch_bounds__(256) void final_k(float* __restrict__ o,
                                               const __bf16* __restrict__ t2,
                                               const __bf16* __restrict__ tsc,
                                               const float* __restrict__ a2,
                                               const float* __restrict__ b2,
                                               const float* __restrict__ asc,
                                               const float* __restrict__ bsc) {
  const int idx = (blockIdx.x << 8) + threadIdx.x;
  const int c = (idx << 2) & 255;
  const bf4 tv = *(const bf4*)&t2[(size_t)idx << 2];
  const bf4 sv = *(const bf4*)&tsc[(size_t)idx << 2];
  float4 r;
  r.x = lk(a2[c + 0] * bf2f(tv[0]) + b2[c + 0]) + asc[c + 0] * bf2f(sv[0]) + bsc[c + 0];
  r.y = lk(a2[c + 1] * bf2f(tv[1]) + b2[c + 1]) + asc[c + 1] * bf2f(sv[1]) + bsc[c + 1];
  r.z = lk(a2[c + 2] * bf2f(tv[2]) + b2[c + 2]) + asc[c + 2] * bf2f(sv[2]) + bsc[c + 2];
  r.w = lk(a2[c + 3] * bf2f(tv[3]) + b2[c + 3]) + asc[c + 3] * bf2f(sv[3]) + bsc[c + 3];
  ((float4*)o)[idx] = r;
}

// ---------------------------------------------------------------------------
// Counting sort of edges by e_query
// ---------------------------------------------------------------------------
__global__ __launch_bounds__(256) void hist_k(const int* __restrict__ eq, int* __restrict__ cnt) {
  const int stride = gridDim.x << 8;
  for (int e = (blockIdx.x << 8) + threadIdx.x; e < EDG; e += stride)
    atomicAdd(&cnt[eq[e]], 1);
}

__global__ __launch_bounds__(256) void scanA_k(const int* __restrict__ cnt, int* __restrict__ part) {
  __shared__ int s[256];
  const int tid = threadIdx.x;
  const int base = blockIdx.x * SCH;
  int acc = 0;
  for (int i = tid; i < SCH; i += 256) {
    const int idx = base + i;
    if (idx < NP) acc += cnt[idx];
  }
  s[tid] = acc;
  __syncthreads();
  for (int d = 128; d > 0; d >>= 1) {
    if (tid < d) s[tid] += s[tid + d];
    __syncthreads();
  }
  if (tid == 0) part[blockIdx.x] = s[0];
}

__global__ void scanB_k(int* __restrict__ part, int* __restrict__ off) {
  if (threadIdx.x == 0) {
    int run = 0;
    for (int i = 0; i < SNB; ++i) { const int v = part[i]; part[i] = run; run += v; }
    off[NP] = EDG;
  }
}

__global__ __launch_bounds__(256) void scanC_k(const int* __restrict__ cnt,
                                               const int* __restrict__ part,
                                               int* __restrict__ off, int* __restrict__ cur) {
  __shared__ int s[256];
  const int tid = threadIdx.x;
  const int base = blockIdx.x * SCH + tid * 8;
  int loc[8];
  int mysum = 0;
#pragma unroll
  for (int j = 0; j < 8; ++j) {
    const int idx = base + j;
    const int v = (idx < NP) ? cnt[idx] : 0;
    loc[j] = mysum;
    mysum += v;
  }
  s[tid] = mysum;
  __syncthreads();
  for (int d = 1; d < 256; d <<= 1) {
    int v = (tid >= d) ? s[tid - d] : 0;
    __syncthreads();
    s[tid] += v;
    __syncthreads();
  }
  const int tb = part[blockIdx.x] + s[tid] - mysum;
#pragma unroll
  for (int j = 0; j < 8; ++j) {
    const int idx = base + j;
    if (idx < NP) { off[idx] = tb + loc[j]; cur[idx] = tb + loc[j]; }
  }
}

__global__ __launch_bounds__(256) void scat_k(const int* __restrict__ er,
                                              const int* __restrict__ eq,
                                              int* __restrict__ cur, int* __restrict__ sref) {
  const int stride = gridDim.x << 8;
  for (int e = (blockIdx.x << 8) + threadIdx.x; e < EDG; e += stride) {
    const int p = atomicAdd(&cur[eq[e]], 1);
    sref[p] = er[e];
  }
}

// ---------------------------------------------------------------------------
// One-shot preshuffle of all weights into bf16 MFMA B-frag layouts.
// Generic: Wp[((ks*NTG+ntg)*64+lane)*8+j] = W[(ks*32+(lane>>4)*8+j)*Ntot + ntg*16+(lane&15)]
// Segments: W1p[8192] | Wscp[32768] | W2p[16384] | Wfp[61440]
// ---------------------------------------------------------------------------
__device__ __forceinline__ void wshuf1(const float* W, __bf16* Wp, int idx, int Ntot) {
  const int j = idx & 7;
  const int lane = (idx >> 3) & 63;
  const int rest = idx >> 9;
  const int NTG = Ntot >> 4;
  const int ntg = rest % NTG;
  const int ks = rest / NTG;
  Wp[idx] = (__bf16)W[(size_t)(ks * 32 + ((lane >> 4) << 3) + j) * Ntot + ntg * 16 + (lane & 15)];
}

__global__ __launch_bounds__(256) void allshuf_k(const float* __restrict__ W1,
                                                 const float* __restrict__ Wsc,
                                                 const float* __restrict__ W2,
                                                 const float* __restrict__ Wkp,
                                                 __bf16* __restrict__ base) {
  const int i = (blockIdx.x << 8) + threadIdx.x;
  if (i < 8192) {
    wshuf1(W1, base, i, 64);
  } else if (i < 40960) {
    wshuf1(Wsc, base + 8192, i - 8192, 256);
  } else if (i < 57344) {
    wshuf1(W2, base + 40960, i - 40960, 256);
  } else if (i < 118784) {
    const int idx = i - 57344;
    const int j = idx & 7;
    const int lane = (idx >> 3) & 63;
    const int nt = (idx >> 9) & 3;
    const int kb = (idx >> 11) & 1;
    const int k = idx >> 12;
    const int kd = kb * 32 + ((lane >> 4) << 3) + j;
    const int n = nt * 16 + (lane & 15);
    (base + 57344)[idx] = (__bf16)Wkp[(k * 64 + kd) * 64 + n];
  }
}

// ---------------------------------------------------------------------------
// KPConv gather: block = 16 queries (256 thr).
// Stage 1 (edge-parallel): refs, active-k masks, half-precision influences -> LDS.
// Stage 2: per wave 4 queries; 4 edges of ONE query in parallel (lane=esub*16+t),
//   prefetched bf16 h gather, ds_add_f32 accumulation into agg (race-free across
//   waves: disjoint queries; within-wave races resolved by LDS atomics).
// Phase B: y[16x64] = sum_k agg[:,k,:] @ W_k via bf16 MFMA (preshuffled Wf).
// LDS ~80.9KB -> 2 blocks/CU.
// ---------------------------------------------------------------------------
__global__ __launch_bounds__(256) void kpagg_k(const float* __restrict__ pos,
                                               const int* __restrict__ sref,
                                               const int* __restrict__ off,
                                               const float* __restrict__ kpts,
                                               const __bf16* __restrict__ Wf,
                                               const __bf16* __restrict__ hb,
                                               float* __restrict__ y) {
  __shared__ float agg[16 * NK * AK];   // 65,280 B
  __shared__ int refsL[MAXE];           // 1,536
  __shared__ int maskL[MAXE];           // 1,536
  __shared__ half_t inflL[MAXE * 16];   // 12,288
  __shared__ int qoffL[17];
  __shared__ float kpL[48];

  const int tid = threadIdx.x;
  const int q0 = blockIdx.x << 4;
  if (tid < 17) qoffL[tid] = off[q0 + tid];
  if (tid >= 32 && tid < 32 + 45) kpL[tid - 32] = kpts[tid - 32];
  for (int i = tid; i < 16 * NK * AK / 4; i += 256) ((float4*)agg)[i] = make_float4(0, 0, 0, 0);
  __syncthreads();

  const int e0 = qoffL[0];
  int nE = qoffL[16] - e0;
  if (nE > MAXE) nE = MAXE;

  // ---- stage 1 ----
  for (int i = tid; i < nE; i += 256) {
    const int e = e0 + i;
    const int ref = sref[e];
    refsL[i] = ref;
    int lo = 0, hi = 16;
    while (hi - lo > 1) { const int mid = (lo + hi) >> 1; if (qoffL[mid] <= e) lo = mid; else hi = mid; }
    const int q = q0 + lo;
    const float4 pr = *(const float4*)&pos[ref * 4];
    const float4 pq = *(const float4*)&pos[q * 4];
    const float rx = pr.y - pq.y, ry = pr.z - pq.z, rz = pr.w - pq.w;
    int m = 0;
#pragma unroll
    for (int k = 0; k < NK; ++k) {
      const float dx = rx - kpL[k * 3 + 0];
      const float dy = ry - kpL[k * 3 + 1];
      const float dz = rz - kpL[k * 3 + 2];
      const float w = 1.f - sqrtf(dx * dx + dy * dy + dz * dz) * (1.f / SIGK);
      const float wc = w > 0.f ? w : 0.f;
      inflL[i * 16 + k] = (half_t)wc;
      if (w > 0.f) m |= (1 << k);
    }
    maskL[i] = m;
  }
  __syncthreads();

  // ---- stage 2 ----
  const int wv = tid >> 6, lane = tid & 63;
  const int esub = lane >> 4, t = lane & 15;
  for (int qi = 0; qi < 4; ++qi) {
    const int ql = (wv << 2) + qi;
    const int le0 = qoffL[ql] - e0;
    int le1 = qoffL[ql + 1] - e0;
    if (le1 > nE) le1 = nE;
    if (le0 >= le1) continue;
    float* aggq = &agg[ql * (NK * AK)];
    // prefetch first
    int jn = le0 + esub;
    bool actn = jn < le1;
    int mn = actn ? maskL[jn] : 0;
    int refn = refsL[actn ? jn : le0];
    bf4 hn = *(const bf4*)&hb[(size_t)refn * 64 + (t << 2)];
    int jcur = jn;
    for (int j0 = le0; j0 < le1; j0 += 4) {
      int m = mn;
      const bf4 hv = hn;
      const int j = jcur;
      // prefetch next step
      jn = j0 + 4 + esub;
      actn = jn < le1;
      mn = actn ? maskL[jn] : 0;
      refn = refsL[actn ? jn : le0];
      hn = *(const bf4*)&hb[(size_t)refn * 64 + (t << 2)];
      jcur = jn;
      const float f0 = bf2f(hv[0]), f1 = bf2f(hv[1]), f2 = bf2f(hv[2]), f3 = bf2f(hv[3]);
      while (m) {
        const int k = __builtin_ctz(m);
        m &= m - 1;
        const float w = (float)inflL[j * 16 + k];
        float* a = &aggq[k * AK + (t << 2)];
        atomicAdd(a + 0, w * f0);
        atomicAdd(a + 1, w * f1);
        atomicAdd(a + 2, w * f2);
        atomicAdd(a + 3, w * f3);
      }
    }
  }
  __syncthreads();

  // ---- phase B: MFMA ----
  const int mrow = lane & 15;
  const int kq = lane >> 4;
  v4f acc = {0.f, 0.f, 0.f, 0.f};
  const v8bf* Wf8 = (const v8bf*)Wf;
#pragma unroll
  for (int k = 0; k < NK; ++k) {
#pragma unroll
    for (int kb = 0; kb < 2; ++kb) {
      const float* ap = &agg[mrow * (NK * AK) + k * AK + kb * 32 + (kq << 3)];
      const float4 al = *(const float4*)ap;
      const float4 ah = *(const float4*)(ap + 4);
      v8bf av;
      av[0] = (__bf16)al.x; av[1] = (__bf16)al.y; av[2] = (__bf16)al.z; av[3] = (__bf16)al.w;
      av[4] = (__bf16)ah.x; av[5] = (__bf16)ah.y; av[6] = (__bf16)ah.z; av[7] = (__bf16)ah.w;
      const v8bf bv = Wf8[((k * 2 + kb) * 4 + wv) * 64 + lane];
      acc = __builtin_amdgcn_mfma_f32_16x16x32_bf16(av, bv, acc, 0, 0, 0);
    }
  }
#pragma unroll
  for (int r = 0; r < 4; ++r) {
    const int row = (lane >> 4) * 4 + r;
    const int col = wv * 16 + (lane & 15);
    y[(size_t)(q0 + row) * 64 + col] = acc[r];
  }
}

// ---------------------------------------------------------------------------
extern "C" void kernel_launch(void* const* d_in, const int* in_sizes, int n_in,
                              void* d_out, int out_size, void* d_ws, size_t ws_size,
                              hipStream_t stream) {
  const float* pos = (const float*)d_in[0];
  const float* x   = (const float*)d_in[1];
  const int* er    = (const int*)d_in[2];
  const int* eq    = (const int*)d_in[3];
  const float* W1  = (const float*)d_in[4];
  const float* g1  = (const float*)d_in[5];
  const float* b1  = (const float*)d_in[6];
  const float* kp  = (const float*)d_in[7];
  const float* Wkp = (const float*)d_in[8];
  const float* gkp = (const float*)d_in[9];
  const float* bkp = (const float*)d_in[10];
  const float* W2  = (const float*)d_in[11];
  const float* g2  = (const float*)d_in[12];
  const float* b2  = (const float*)d_in[13];
  const float* Wsc = (const float*)d_in[14];
  const float* gsc = (const float*)d_in[15];
  const float* bsc = (const float*)d_in[16];
  float* out = (float*)d_out;
  float* ws = (float*)d_ws;

  // stats / affine scratch (first 4096 floats)
  float* sum1 = ws;          float* sq1  = ws + 64;
  float* sumsc = ws + 128;   float* sqsc = ws + 384;
  float* sumy = ws + 640;    float* sqy  = ws + 704;
  float* sum2 = ws + 768;    float* sq2  = ws + 1024;
  float* a1v = ws + 1280;    float* b1v  = ws + 1344;
  float* ascv = ws + 1408;   float* bscv = ws + 1664;
  float* ayv = ws + 1920;    float* byv  = ws + 1984;
  float* a2v = ws + 2048;    float* b2v  = ws + 2304;

  // layout (float offsets)
  __bf16* Wpb = (__bf16*)(ws + 4096);            // 118,784 bf16 (in 65,536 floats)
  __bf16* W1p = Wpb;
  __bf16* Wscp = Wpb + 8192;
  __bf16* W2p = Wpb + 40960;
  __bf16* Wfp = Wpb + 57344;
  float* hbB = ws + 69632;                       // hb bf16 [N*64] in 3.2M floats
  __bf16* hb = (__bf16*)hbB;
  float* ybuf = ws + 69632 + 3200000;            // fp32 [N*64]
  float* hbuf = ybuf + 6400000;                  // fp32 [N*64]
  __bf16* tscb = (__bf16*)ybuf;                  // bf16 [N*256] overlays ybuf+hbuf
  int* cnt = (int*)(hbuf + 6400000);             // sort region
  int* off = cnt + 100352;
  int* cur = off + 100352;
  int* part = cur + 100352;
  int* sref = part + 256;
  __bf16* t2b = (__bf16*)cnt;                    // bf16 [N*256] overlays sort region

  const float invn = 1.f / (float)NP;

  (void)hipMemsetAsync(ws, 0, 4096 * sizeof(float), stream);
  (void)hipMemsetAsync(cnt, 0, 100352 * sizeof(int), stream);

  // weight preshuffle (all four)
  allshuf_k<<<464, 256, 0, stream>>>(W1, Wsc, W2, Wkp, Wpb);

  // unary_1: hbuf = x@W1 (stats fused) ; fold ; hb = bf16(leaky(BN))
  mgemm_k<128, 64, false, false><<<dim3(782, 1), 256, 0, stream>>>(
      x, W1p, hbuf, NP, 64, nullptr, nullptr, sum1, sq1);
  finalize_k<<<1, 256, 0, stream>>>(sum1, sq1, g1, b1, a1v, b1v, 64, invn);
  normleaky_k<<<6250, 256, 0, stream>>>(hbuf, hb, a1v, b1v);

  // edge sort by query
  hist_k<<<2048, 256, 0, stream>>>(eq, cnt);
  scanA_k<<<SNB, 256, 0, stream>>>(cnt, part);
  scanB_k<<<1, 64, 0, stream>>>(part, off);
  scanC_k<<<SNB, 256, 0, stream>>>(cnt, part, off, cur);
  scat_k<<<2048, 256, 0, stream>>>(er, eq, cur, sref);

  // KPConv
  kpagg_k<<<6250, 256, 0, stream>>>(pos, sref, off, kp, Wfp, hb, ybuf);
  colstats_k<64><<<512, 256, 0, stream>>>(ybuf, NP * 64, sumy, sqy);
  finalize_k<<<1, 256, 0, stream>>>(sumy, sqy, gkp, bkp, ayv, byv, 64, invn);

  // unary_2: t2b = bf16( leaky(BN(y)) @ W2 ), stats fused (overwrites sort bufs)
  mgemm_k<64, 128, true, true><<<dim3(782, 2), 256, 0, stream>>>(
      ybuf, W2p, t2b, NP, 256, ayv, byv, sum2, sq2);
  finalize_k<<<1, 256, 0, stream>>>(sum2, sq2, g2, b2, a2v, b2v, 256, invn);

  // shortcut: tscb = bf16( x@Wsc ), stats fused (overwrites ybuf/hbuf)
  mgemm_k<128, 128, false, true><<<dim3(782, 2), 256, 0, stream>>>(
      x, Wscp, tscb, NP, 256, nullptr, nullptr, sumsc, sqsc);
  finalize_k<<<1, 256, 0, stream>>>(sumsc, sqsc, gsc, bsc, ascv, bscv, 256, invn);

  // out = leaky(BN(t2)) + BN(tsc)
  final_k<<<25000, 256, 0, stream>>>(out, t2b, tscb, a2v, b2v, ascv, bscv);
}

// Round 4
// 766.566 us; speedup vs baseline: 2.2990x; 2.2990x over previous
//
#include <hip/hip_runtime.h>
#include <math.h>

#define NP   100000
#define EDG  1600000
#define NK   15
#define SIGK 0.04f
#define SCH  2048
#define SNB  49            // ceil(NP/SCH)
#define MAXE 384           // max edges per 16-query block (mean 256, sigma 16)
#define AGP  968           // agg pitch in bf16 (960 + 8 pad)

typedef __bf16 v8bf __attribute__((ext_vector_type(8)));
typedef __bf16 bf4  __attribute__((ext_vector_type(4)));
typedef float  v4f  __attribute__((ext_vector_type(4)));

__device__ __forceinline__ float lk(float v) { return v >= 0.f ? v : 0.1f * v; }
__device__ __forceinline__ float bf2f(__bf16 b) { return (float)b; }

// ---------------------------------------------------------------------------
// MFMA GEMM: Out[n x Ntot] = X[n x KIN] @ W, W preshuffled bf16 B-frags.
// Block 256 thr = 4 waves; tile 128 rows x NB cols. Column stats fused.
// ---------------------------------------------------------------------------
template <int KIN, int NB, bool TRANS, bool OUTBF>
__global__ __launch_bounds__(256) void mgemm_k(const float* __restrict__ X,
                                               const __bf16* __restrict__ Wp,
                                               void* __restrict__ Out, int n, int Ntot,
                                               const float* __restrict__ ta,
                                               const float* __restrict__ tb,
                                               float* __restrict__ osum,
                                               float* __restrict__ osq) {
  constexpr int PITCH = KIN + 8;
  constexpr int NT = NB / 16;
  __shared__ __bf16 al[128 * PITCH];
  __shared__ float red[2][NB][4];
  const int tid = threadIdx.x;
  const int r0 = blockIdx.x << 7;
  const int nb0 = blockIdx.y * NB;

  constexpr int QKS = (KIN == 128) ? 5 : 4;  // log2(KIN/4)
  for (int idx = tid; idx < (128 << QKS); idx += 256) {
    const int r = idx >> QKS, q = (idx & ((1 << QKS) - 1)) << 2;
    const int row = r0 + r;
    float4 v = make_float4(0.f, 0.f, 0.f, 0.f);
    if (row < n) {
      v = *(const float4*)&X[(size_t)row * KIN + q];
      if (TRANS) {
        v.x = lk(ta[q + 0] * v.x + tb[q + 0]);
        v.y = lk(ta[q + 1] * v.y + tb[q + 1]);
        v.z = lk(ta[q + 2] * v.z + tb[q + 2]);
        v.w = lk(ta[q + 3] * v.w + tb[q + 3]);
      }
    }
    bf4 o;
    o[0] = (__bf16)v.x; o[1] = (__bf16)v.y; o[2] = (__bf16)v.z; o[3] = (__bf16)v.w;
    *(bf4*)&al[r * PITCH + q] = o;
  }
  __syncthreads();

  const int wv = tid >> 6, lane = tid & 63;
  const int mr = lane & 15, quad = lane >> 4;
  const int ntg0 = nb0 >> 4;
  const int NTG = Ntot >> 4;
  v4f acc[2][NT];
#pragma unroll
  for (int a = 0; a < 2; ++a)
#pragma unroll
    for (int b = 0; b < NT; ++b) acc[a][b] = (v4f){0.f, 0.f, 0.f, 0.f};

#pragma unroll
  for (int ks = 0; ks < KIN / 32; ++ks) {
    v8bf bf[NT];
#pragma unroll
    for (int nt = 0; nt < NT; ++nt)
      bf[nt] = ((const v8bf*)Wp)[((size_t)ks * NTG + ntg0 + nt) * 64 + lane];
#pragma unroll
    for (int mt = 0; mt < 2; ++mt) {
      const int row = (wv << 5) + (mt << 4) + mr;
      const v8bf av = *(const v8bf*)&al[row * PITCH + (ks << 5) + (quad << 3)];
#pragma unroll
      for (int nt = 0; nt < NT; ++nt)
        acc[mt][nt] = __builtin_amdgcn_mfma_f32_16x16x32_bf16(av, bf[nt], acc[mt][nt], 0, 0, 0);
    }
  }

  float csum[NT], csq[NT];
#pragma unroll
  for (int nt = 0; nt < NT; ++nt) { csum[nt] = 0.f; csq[nt] = 0.f; }
#pragma unroll
  for (int mt = 0; mt < 2; ++mt)
#pragma unroll
    for (int nt = 0; nt < NT; ++nt)
#pragma unroll
      for (int r = 0; r < 4; ++r) {
        const float v = acc[mt][nt][r];
        const int row = r0 + (wv << 5) + (mt << 4) + (quad << 2) + r;
        if (row < n) {
          const size_t o = (size_t)row * Ntot + nb0 + (nt << 4) + mr;
          if (OUTBF) ((__bf16*)Out)[o] = (__bf16)v;
          else       ((float*)Out)[o] = v;
        }
        csum[nt] += v;
        csq[nt] += v * v;
      }
#pragma unroll
  for (int nt = 0; nt < NT; ++nt) {
    float s = csum[nt], q = csq[nt];
    s += __shfl_down(s, 32); s += __shfl_down(s, 16);
    q += __shfl_down(q, 32); q += __shfl_down(q, 16);
    if (quad == 0) { red[0][(nt << 4) + mr][wv] = s; red[1][(nt << 4) + mr][wv] = q; }
  }
  __syncthreads();
  if (tid < NB) {
    const float s = red[0][tid][0] + red[0][tid][1] + red[0][tid][2] + red[0][tid][3];
    const float q = red[1][tid][0] + red[1][tid][1] + red[1][tid][2] + red[1][tid][3];
    atomicAdd(&osum[nb0 + tid], s);
    atomicAdd(&osq[nb0 + tid], q);
  }
}

// ---------------------------------------------------------------------------
__global__ void finalize_k(const float* __restrict__ sum, const float* __restrict__ sq,
                           const float* __restrict__ g, const float* __restrict__ b,
                           float* __restrict__ oa, float* __restrict__ ob, int C,
                           float invn) {
  const int c = threadIdx.x;
  if (c < C) {
    const float m = sum[c] * invn;
    const float var = sq[c] * invn - m * m;
    const float a = g[c] / sqrtf(var + 1e-5f);
    oa[c] = a;
    ob[c] = b[c] - m * a;
  }
}

// t1 bf16 -> hb bf16 with affine+leaky
__global__ __launch_bounds__(256) void normleaky_k(const __bf16* __restrict__ t,
                                                   __bf16* __restrict__ hb,
                                                   const float* __restrict__ a,
                                                   const float* __restrict__ b) {
  const int idx = (blockIdx.x << 8) + threadIdx.x;
  const int c = (idx << 2) & 63;
  const bf4 v = *(const bf4*)&t[(size_t)idx << 2];
  bf4 o;
  o[0] = (__bf16)lk(a[c + 0] * bf2f(v[0]) + b[c + 0]);
  o[1] = (__bf16)lk(a[c + 1] * bf2f(v[1]) + b[c + 1]);
  o[2] = (__bf16)lk(a[c + 2] * bf2f(v[2]) + b[c + 2]);
  o[3] = (__bf16)lk(a[c + 3] * bf2f(v[3]) + b[c + 3]);
  *(bf4*)&hb[(size_t)idx << 2] = o;
}

// out = leaky(a2*t2+b2) + asc*tsc+bsc   (t2, tsc bf16)
__global__ __launch_bounds__(256) void final_k(float* __restrict__ o,
                                               const __bf16* __restrict__ t2,
                                               const __bf16* __restrict__ tsc,
                                               const float* __restrict__ a2,
                                               const float* __restrict__ b2,
                                               const float* __restrict__ asc,
                                               const float* __restrict__ bsc) {
  const int idx = (blockIdx.x << 8) + threadIdx.x;
  const int c = (idx << 2) & 255;
  const bf4 tv = *(const bf4*)&t2[(size_t)idx << 2];
  const bf4 sv = *(const bf4*)&tsc[(size_t)idx << 2];
  float4 r;
  r.x = lk(a2[c + 0] * bf2f(tv[0]) + b2[c + 0]) + asc[c + 0] * bf2f(sv[0]) + bsc[c + 0];
  r.y = lk(a2[c + 1] * bf2f(tv[1]) + b2[c + 1]) + asc[c + 1] * bf2f(sv[1]) + bsc[c + 1];
  r.z = lk(a2[c + 2] * bf2f(tv[2]) + b2[c + 2]) + asc[c + 2] * bf2f(sv[2]) + bsc[c + 2];
  r.w = lk(a2[c + 3] * bf2f(tv[3]) + b2[c + 3]) + asc[c + 3] * bf2f(sv[3]) + bsc[c + 3];
  ((float4*)o)[idx] = r;
}

// ---------------------------------------------------------------------------
// Counting sort of edges by e_query
// ---------------------------------------------------------------------------
__global__ __launch_bounds__(256) void hist_k(const int* __restrict__ eq, int* __restrict__ cnt) {
  const int stride = gridDim.x << 8;
  for (int e = (blockIdx.x << 8) + threadIdx.x; e < EDG; e += stride)
    atomicAdd(&cnt[eq[e]], 1);
}

__global__ __launch_bounds__(256) void scanA_k(const int* __restrict__ cnt, int* __restrict__ part) {
  __shared__ int s[256];
  const int tid = threadIdx.x;
  const int base = blockIdx.x * SCH;
  int acc = 0;
  for (int i = tid; i < SCH; i += 256) {
    const int idx = base + i;
    if (idx < NP) acc += cnt[idx];
  }
  s[tid] = acc;
  __syncthreads();
  for (int d = 128; d > 0; d >>= 1) {
    if (tid < d) s[tid] += s[tid + d];
    __syncthreads();
  }
  if (tid == 0) part[blockIdx.x] = s[0];
}

__global__ void scanB_k(int* __restrict__ part, int* __restrict__ off) {
  if (threadIdx.x == 0) {
    int run = 0;
    for (int i = 0; i < SNB; ++i) { const int v = part[i]; part[i] = run; run += v; }
    off[NP] = EDG;
  }
}

__global__ __launch_bounds__(256) void scanC_k(const int* __restrict__ cnt,
                                               const int* __restrict__ part,
                                               int* __restrict__ off, int* __restrict__ cur) {
  __shared__ int s[256];
  const int tid = threadIdx.x;
  const int base = blockIdx.x * SCH + tid * 8;
  int loc[8];
  int mysum = 0;
#pragma unroll
  for (int j = 0; j < 8; ++j) {
    const int idx = base + j;
    const int v = (idx < NP) ? cnt[idx] : 0;
    loc[j] = mysum;
    mysum += v;
  }
  s[tid] = mysum;
  __syncthreads();
  for (int d = 1; d < 256; d <<= 1) {
    int v = (tid >= d) ? s[tid - d] : 0;
    __syncthreads();
    s[tid] += v;
    __syncthreads();
  }
  const int tb = part[blockIdx.x] + s[tid] - mysum;
#pragma unroll
  for (int j = 0; j < 8; ++j) {
    const int idx = base + j;
    if (idx < NP) { off[idx] = tb + loc[j]; cur[idx] = tb + loc[j]; }
  }
}

__global__ __launch_bounds__(256) void scat_k(const int* __restrict__ er,
                                              const int* __restrict__ eq,
                                              int* __restrict__ cur, int* __restrict__ sref) {
  const int stride = gridDim.x << 8;
  for (int e = (blockIdx.x << 8) + threadIdx.x; e < EDG; e += stride) {
    const int p = atomicAdd(&cur[eq[e]], 1);
    sref[p] = er[e];
  }
}

// ---------------------------------------------------------------------------
// One-shot preshuffle of all weights into bf16 MFMA B-frag layouts.
// ---------------------------------------------------------------------------
__device__ __forceinline__ void wshuf1(const float* W, __bf16* Wp, int idx, int Ntot) {
  const int j = idx & 7;
  const int lane = (idx >> 3) & 63;
  const int rest = idx >> 9;
  const int NTG = Ntot >> 4;
  const int ntg = rest % NTG;
  const int ks = rest / NTG;
  Wp[idx] = (__bf16)W[(size_t)(ks * 32 + ((lane >> 4) << 3) + j) * Ntot + ntg * 16 + (lane & 15)];
}

__global__ __launch_bounds__(256) void allshuf_k(const float* __restrict__ W1,
                                                 const float* __restrict__ Wsc,
                                                 const float* __restrict__ W2,
                                                 const float* __restrict__ Wkp,
                                                 __bf16* __restrict__ base) {
  const int i = (blockIdx.x << 8) + threadIdx.x;
  if (i < 8192) {
    wshuf1(W1, base, i, 64);
  } else if (i < 40960) {
    wshuf1(Wsc, base + 8192, i - 8192, 256);
  } else if (i < 57344) {
    wshuf1(W2, base + 40960, i - 40960, 256);
  } else if (i < 118784) {
    const int idx = i - 57344;
    const int j = idx & 7;
    const int lane = (idx >> 3) & 63;
    const int nt = (idx >> 9) & 3;
    const int kb = (idx >> 11) & 1;
    const int k = idx >> 12;
    const int kd = kb * 32 + ((lane >> 4) << 3) + j;
    const int n = nt * 16 + (lane & 15);
    (base + 57344)[idx] = (__bf16)Wkp[(k * 64 + kd) * 64 + n];
  }
}

// ---------------------------------------------------------------------------
// KPConv gather: block = 16 queries (256 thr).
// Stage 1 (edge-parallel): refs + fp32 influences (zeros where inactive) -> LDS.
// Stage 2: lane owns (query, 4-ch chunk) EXCLUSIVELY; register accumulators
//   acc[15][4]; per edge: broadcast LDS reads of infl + prefetched bf16 h
//   gather; 60 unconditional v_fma. No LDS RMW, no atomics, no divergent mask
//   loop. agg written once to LDS as bf16 in A-frag-friendly layout.
// Phase B: y[16x64] = sum_k agg @ W_k via MFMA; column stats fused (atomics).
// LDS ~57.4 KB -> 2 blocks/CU.
// ---------------------------------------------------------------------------
__global__ __launch_bounds__(256) void kpagg_k(const float* __restrict__ pos,
                                               const int* __restrict__ sref,
                                               const int* __restrict__ off,
                                               const float* __restrict__ kpts,
                                               const __bf16* __restrict__ Wf,
                                               const __bf16* __restrict__ hb,
                                               float* __restrict__ y,
                                               float* __restrict__ osum,
                                               float* __restrict__ osq) {
  __shared__ __bf16 aggL[16 * AGP];     // 30,976 B
  __shared__ float inflF[MAXE * 16];    // 24,576 B (k=15 column zeroed)
  __shared__ int refsL[MAXE];           // 1,536 B
  __shared__ int qoffL[17];
  __shared__ float kpL[48];

  const int tid = threadIdx.x;
  const int q0 = blockIdx.x << 4;
  if (tid < 17) qoffL[tid] = off[q0 + tid];
  if (tid >= 32 && tid < 32 + 45) kpL[tid - 32] = kpts[tid - 32];
  __syncthreads();

  const int e0 = qoffL[0];
  int nE = qoffL[16] - e0;
  if (nE > MAXE) nE = MAXE;

  // ---- stage 1: edge-parallel influence compute ----
  for (int i = tid; i < nE; i += 256) {
    const int e = e0 + i;
    const int ref = sref[e];
    refsL[i] = ref;
    int lo = 0, hi = 16;
    while (hi - lo > 1) { const int mid = (lo + hi) >> 1; if (qoffL[mid] <= e) lo = mid; else hi = mid; }
    const int q = q0 + lo;
    const float4 pr = *(const float4*)&pos[ref * 4];
    const float4 pq = *(const float4*)&pos[q * 4];
    const float rx = pr.y - pq.y, ry = pr.z - pq.z, rz = pr.w - pq.w;
#pragma unroll
    for (int k = 0; k < NK; ++k) {
      const float dx = rx - kpL[k * 3 + 0];
      const float dy = ry - kpL[k * 3 + 1];
      const float dz = rz - kpL[k * 3 + 2];
      const float w = 1.f - sqrtf(dx * dx + dy * dy + dz * dz) * (1.f / SIGK);
      inflF[i * 16 + k] = w > 0.f ? w : 0.f;
    }
    inflF[i * 16 + 15] = 0.f;
  }
  __syncthreads();

  // ---- stage 2: register accumulation ----
  const int wv = tid >> 6, lane = tid & 63;
  const int ql = (wv << 2) + (lane >> 4);   // query owned by this lane
  const int t4 = (lane & 15) << 2;          // channel chunk
  const int le0 = qoffL[ql] - e0;
  int le1 = qoffL[ql + 1] - e0;
  if (le1 > nE) le1 = nE;

  float acc[NK][4];
#pragma unroll
  for (int k = 0; k < NK; ++k) { acc[k][0] = acc[k][1] = acc[k][2] = acc[k][3] = 0.f; }

  int refn = refsL[(le0 < le1) ? le0 : 0];
  bf4 hn = *(const bf4*)&hb[(size_t)refn * 64 + t4];
#pragma unroll 1
  for (int j = le0; j < le1; ++j) {
    const bf4 hv = hn;
    const int jn = (j + 1 < le1) ? j + 1 : j;
    refn = refsL[jn];
    hn = *(const bf4*)&hb[(size_t)refn * 64 + t4];   // prefetch next
    const float f0 = bf2f(hv[0]), f1 = bf2f(hv[1]), f2 = bf2f(hv[2]), f3 = bf2f(hv[3]);
    const float4 wA = *(const float4*)&inflF[j * 16 + 0];
    const float4 wB = *(const float4*)&inflF[j * 16 + 4];
    const float4 wC = *(const float4*)&inflF[j * 16 + 8];
    const float4 wD = *(const float4*)&inflF[j * 16 + 12];
    const float wk[NK] = {wA.x, wA.y, wA.z, wA.w, wB.x, wB.y, wB.z, wB.w,
                          wC.x, wC.y, wC.z, wC.w, wD.x, wD.y, wD.z};
#pragma unroll
    for (int k = 0; k < NK; ++k) {
      acc[k][0] += wk[k] * f0;
      acc[k][1] += wk[k] * f1;
      acc[k][2] += wk[k] * f2;
      acc[k][3] += wk[k] * f3;
    }
  }

  // write agg (bf16) for phase B
#pragma unroll
  for (int k = 0; k < NK; ++k) {
    bf4 o;
    o[0] = (__bf16)acc[k][0]; o[1] = (__bf16)acc[k][1];
    o[2] = (__bf16)acc[k][2]; o[3] = (__bf16)acc[k][3];
    *(bf4*)&aggL[ql * AGP + k * 64 + t4] = o;
  }
  __syncthreads();

  // ---- phase B: MFMA y = agg @ Wk, wave wv -> cols [wv*16, wv*16+16) ----
  const int m = lane & 15, quad = lane >> 4;
  v4f yacc = {0.f, 0.f, 0.f, 0.f};
  const v8bf* Wf8 = (const v8bf*)Wf;
#pragma unroll
  for (int k = 0; k < NK; ++k)
#pragma unroll
    for (int kb = 0; kb < 2; ++kb) {
      const v8bf av = *(const v8bf*)&aggL[m * AGP + k * 64 + kb * 32 + (quad << 3)];
      const v8bf bv = Wf8[((k * 2 + kb) * 4 + wv) * 64 + lane];
      yacc = __builtin_amdgcn_mfma_f32_16x16x32_bf16(av, bv, yacc, 0, 0, 0);
    }

  float s = 0.f, q2 = 0.f;
#pragma unroll
  for (int r = 0; r < 4; ++r) {
    const float v = yacc[r];
    y[(size_t)(q0 + (quad << 2) + r) * 64 + (wv << 4) + m] = v;
    s += v; q2 += v * v;
  }
  s += __shfl_down(s, 32); s += __shfl_down(s, 16);
  q2 += __shfl_down(q2, 32); q2 += __shfl_down(q2, 16);
  if (quad == 0) {
    atomicAdd(&osum[(wv << 4) + m], s);
    atomicAdd(&osq[(wv << 4) + m], q2);
  }
}

// ---------------------------------------------------------------------------
extern "C" void kernel_launch(void* const* d_in, const int* in_sizes, int n_in,
                              void* d_out, int out_size, void* d_ws, size_t ws_size,
                              hipStream_t stream) {
  const float* pos = (const float*)d_in[0];
  const float* x   = (const float*)d_in[1];
  const int* er    = (const int*)d_in[2];
  const int* eq    = (const int*)d_in[3];
  const float* W1  = (const float*)d_in[4];
  const float* g1  = (const float*)d_in[5];
  const float* b1  = (const float*)d_in[6];
  const float* kp  = (const float*)d_in[7];
  const float* Wkp = (const float*)d_in[8];
  const float* gkp = (const float*)d_in[9];
  const float* bkp = (const float*)d_in[10];
  const float* W2  = (const float*)d_in[11];
  const float* g2  = (const float*)d_in[12];
  const float* b2  = (const float*)d_in[13];
  const float* Wsc = (const float*)d_in[14];
  const float* gsc = (const float*)d_in[15];
  const float* bsc = (const float*)d_in[16];
  float* out = (float*)d_out;
  float* ws = (float*)d_ws;

  // stats / affine scratch (first 4096 floats)
  float* sum1 = ws;          float* sq1  = ws + 64;
  float* sumsc = ws + 128;   float* sqsc = ws + 384;
  float* sumy = ws + 640;    float* sqy  = ws + 704;
  float* sum2 = ws + 768;    float* sq2  = ws + 1024;
  float* a1v = ws + 1280;    float* b1v  = ws + 1344;
  float* ascv = ws + 1408;   float* bscv = ws + 1664;
  float* ayv = ws + 1920;    float* byv  = ws + 1984;
  float* a2v = ws + 2048;    float* b2v  = ws + 2304;

  // layout (float offsets)
  __bf16* Wpb = (__bf16*)(ws + 4096);            // preshuffled weights
  __bf16* W1p = Wpb;
  __bf16* Wscp = Wpb + 8192;
  __bf16* W2p = Wpb + 40960;
  __bf16* Wfp = Wpb + 57344;
  __bf16* hb = (__bf16*)(ws + 69632);            // bf16 [N*64]
  float* ybuf = ws + 69632 + 3200000;            // fp32 [N*64]
  float* t1bf = ybuf + 6400000;                  // bf16 t1 [N*64] region
  __bf16* t1b = (__bf16*)t1bf;
  __bf16* tscb = (__bf16*)ybuf;                  // bf16 [N*256] overlays ybuf+t1b
  int* cnt = (int*)(t1bf + 6400000);             // sort region
  int* off = cnt + 100352;
  int* cur = off + 100352;
  int* part = cur + 100352;
  int* sref = part + 256;
  __bf16* t2b = (__bf16*)cnt;                    // bf16 [N*256] overlays sort region

  const float invn = 1.f / (float)NP;

  (void)hipMemsetAsync(ws, 0, 4096 * sizeof(float), stream);
  (void)hipMemsetAsync(cnt, 0, 100352 * sizeof(int), stream);

  // weight preshuffle
  allshuf_k<<<464, 256, 0, stream>>>(W1, Wsc, W2, Wkp, Wpb);

  // unary_1: t1b = bf16(x@W1) (stats fused) ; fold ; hb = bf16(leaky(BN))
  mgemm_k<128, 64, false, true><<<dim3(782, 1), 256, 0, stream>>>(
      x, W1p, t1b, NP, 64, nullptr, nullptr, sum1, sq1);
  finalize_k<<<1, 256, 0, stream>>>(sum1, sq1, g1, b1, a1v, b1v, 64, invn);
  normleaky_k<<<6250, 256, 0, stream>>>(t1b, hb, a1v, b1v);

  // edge sort by query
  hist_k<<<2048, 256, 0, stream>>>(eq, cnt);
  scanA_k<<<SNB, 256, 0, stream>>>(cnt, part);
  scanB_k<<<1, 64, 0, stream>>>(part, off);
  scanC_k<<<SNB, 256, 0, stream>>>(cnt, part, off, cur);
  scat_k<<<2048, 256, 0, stream>>>(er, eq, cur, sref);

  // KPConv (y stats fused)
  kpagg_k<<<6250, 256, 0, stream>>>(pos, sref, off, kp, Wfp, hb, ybuf, sumy, sqy);
  finalize_k<<<1, 256, 0, stream>>>(sumy, sqy, gkp, bkp, ayv, byv, 64, invn);

  // unary_2: t2b = bf16( leaky(BN(y)) @ W2 ), stats fused (overwrites sort bufs)
  mgemm_k<64, 128, true, true><<<dim3(782, 2), 256, 0, stream>>>(
      ybuf, W2p, t2b, NP, 256, ayv, byv, sum2, sq2);
  finalize_k<<<1, 256, 0, stream>>>(sum2, sq2, g2, b2, a2v, b2v, 256, invn);

  // shortcut: tscb = bf16( x@Wsc ), stats fused (overwrites ybuf/t1b)
  mgemm_k<128, 128, false, true><<<dim3(782, 2), 256, 0, stream>>>(
      x, Wscp, tscb, NP, 256, nullptr, nullptr, sumsc, sqsc);
  finalize_k<<<1, 256, 0, stream>>>(sumsc, sqsc, gsc, bsc, ascv, bscv, 256, invn);

  // out = leaky(BN(t2)) + BN(tsc)
  final_k<<<25000, 256, 0, stream>>>(out, t2b, tscb, a2v, b2v, ascv, bscv);
}